// Round 1
// baseline (71.029 us; speedup 1.0000x reference)
//
#include <hip/hip_runtime.h>

// Problem constants (reference): B=32, L=512, N=128, IN=16, OUT=10
// Pipeline:
//   kA: h = relu(relu(x@W1+b1)@W2+b2)                  (B*L, 64)
//   kB: h_agg = max_l h*tree ; m = relu(h_agg@W3+b3)   (B, N*16)
//   kC: y = relu(m@W4+b4)                              (B, 64)
//   kD: BN(train-mode batch stats) + @W5+b5            (B, 10)

__global__ __launch_bounds__(256) void k_micro(
    const float* __restrict__ x, const float* __restrict__ W1,
    const float* __restrict__ b1, const float* __restrict__ W2,
    const float* __restrict__ b2, float* __restrict__ h)
{
    const int tid = threadIdx.x;
    const int r = tid >> 6;                 // row within block (0..3)
    const int c = tid & 63;                 // channel lane
    const int row = blockIdx.x * 4 + r;     // 0..16383 (= b*512 + l)

    __shared__ float sx[4][16];
    __shared__ float sh1[4][32];

    if (c < 16) sx[r][c] = x[row * 16 + c];
    __syncthreads();

    if (c < 32) {
        float a = b1[c];
        #pragma unroll
        for (int i = 0; i < 16; ++i) a += sx[r][i] * W1[i * 32 + c];
        sh1[r][c] = fmaxf(a, 0.f);
    }
    __syncthreads();

    float a = b2[c];
    #pragma unroll
    for (int j = 0; j < 32; ++j) a += sh1[r][j] * W2[j * 64 + c];
    h[(size_t)row * 64 + c] = fmaxf(a, 0.f);
}

// One block per (node-group of 8, batch b). 256 threads = 4 leaf-phases x 64 ch.
__global__ __launch_bounds__(256) void k_agg_macro(
    const float* __restrict__ h,     // [B][512][64]
    const float* __restrict__ tree,  // [128][512]
    const float* __restrict__ W3, const float* __restrict__ b3,
    float* __restrict__ m)           // [B][2048]
{
    const int ng  = blockIdx.x;      // 0..15 (8 nodes each)
    const int b   = blockIdx.y;      // 0..31
    const int tid = threadIdx.x;
    const int g   = tid >> 6;        // leaf phase 0..3
    const int c   = tid & 63;        // channel

    __shared__ __align__(16) float tl[512][8];   // transposed tree tile
    __shared__ float sred[4][8][64];
    __shared__ float sagg[8][64];

    // stage tree tile transposed: tl[l][n] = tree[ng*8+n][l]
    for (int idx = tid; idx < 8 * 512; idx += 256) {
        int n = idx >> 9, l = idx & 511;
        tl[l][n] = tree[(ng * 8 + n) * 512 + l];
    }
    __syncthreads();

    float acc[8];
    #pragma unroll
    for (int j = 0; j < 8; ++j) acc[j] = 0.f;   // products are >=0, 0-init exact

    const float* hb = h + (size_t)b * 512 * 64 + c;
    #pragma unroll 4
    for (int l = g; l < 512; l += 4) {
        float hv = hb[(size_t)l * 64];
        const float4* tp = (const float4*)&tl[l][0];
        float4 t0 = tp[0], t1 = tp[1];          // 8 node masks, broadcast
        acc[0] = fmaxf(acc[0], hv * t0.x);
        acc[1] = fmaxf(acc[1], hv * t0.y);
        acc[2] = fmaxf(acc[2], hv * t0.z);
        acc[3] = fmaxf(acc[3], hv * t0.w);
        acc[4] = fmaxf(acc[4], hv * t1.x);
        acc[5] = fmaxf(acc[5], hv * t1.y);
        acc[6] = fmaxf(acc[6], hv * t1.z);
        acc[7] = fmaxf(acc[7], hv * t1.w);
    }

    #pragma unroll
    for (int j = 0; j < 8; ++j) sred[g][j][c] = acc[j];
    __syncthreads();

    // combine 4 leaf-phases
    for (int idx = tid; idx < 8 * 64; idx += 256) {
        int n = idx >> 6, cc = idx & 63;
        sagg[n][cc] = fmaxf(fmaxf(sred[0][n][cc], sred[1][n][cc]),
                            fmaxf(sred[2][n][cc], sred[3][n][cc]));
    }
    __syncthreads();

    // fused f_macro: m[n][j] = relu(b3[j] + sum_c h_agg[n][c]*W3[c][j])
    if (tid < 128) {
        int n = tid >> 4, j = tid & 15;
        float a = b3[j];
        #pragma unroll
        for (int cc = 0; cc < 64; ++cc) a += sagg[n][cc] * W3[cc * 16 + j];
        int node = ng * 8 + n;
        m[(size_t)b * 2048 + node * 16 + j] = fmaxf(a, 0.f);
    }
}

// y[b][o] = relu(b4[o] + sum_k m[b][k]*W4[k][o]); one block per b
__global__ __launch_bounds__(256) void k_fout1(
    const float* __restrict__ m, const float* __restrict__ W4,
    const float* __restrict__ b4, float* __restrict__ y)
{
    const int b   = blockIdx.x;
    const int tid = threadIdx.x;
    const int g = tid >> 6, o = tid & 63;

    __shared__ float sm[2048];
    __shared__ float sred[4][64];

    for (int idx = tid; idx < 2048; idx += 256)
        sm[idx] = m[(size_t)b * 2048 + idx];
    __syncthreads();

    float acc = 0.f;
    const float* w = W4 + o;
    #pragma unroll 4
    for (int k = g * 512; k < g * 512 + 512; ++k)
        acc += sm[k] * w[(size_t)k * 64];
    sred[g][o] = acc;
    __syncthreads();

    if (tid < 64) {
        float v = b4[o] + sred[0][o] + sred[1][o] + sred[2][o] + sred[3][o];
        y[b * 64 + o] = fmaxf(v, 0.f);
    }
}

// BatchNorm (training-mode batch stats over B=32) + final linear (64->10)
__global__ __launch_bounds__(320) void k_bn_out(
    const float* __restrict__ y, const float* __restrict__ gamma,
    const float* __restrict__ beta, const float* __restrict__ W5,
    const float* __restrict__ b5, float* __restrict__ out)
{
    const int tid = threadIdx.x;
    __shared__ float smean[64], sscale[64], sbeta[64];
    __shared__ float syn[32 * 64];

    if (tid < 64) {
        float s = 0.f, s2 = 0.f;
        for (int b = 0; b < 32; ++b) {
            float v = y[b * 64 + tid];
            s += v; s2 += v * v;
        }
        float mean = s * (1.f / 32.f);
        float var  = s2 * (1.f / 32.f) - mean * mean;  // biased, as torch BN
        smean[tid]  = mean;
        sscale[tid] = gamma[tid] * rsqrtf(var + 1e-5f);
        sbeta[tid]  = beta[tid];
    }
    __syncthreads();

    for (int idx = tid; idx < 2048; idx += 320) {
        int o = idx & 63;
        syn[idx] = (y[idx] - smean[o]) * sscale[o] + sbeta[o];
    }
    __syncthreads();

    if (tid < 320) {
        int b = tid / 10, q = tid % 10;
        float acc = b5[q];
        #pragma unroll
        for (int o = 0; o < 64; ++o) acc += syn[b * 64 + o] * W5[o * 10 + q];
        out[b * 10 + q] = acc;
    }
}

extern "C" void kernel_launch(void* const* d_in, const int* in_sizes, int n_in,
                              void* d_out, int out_size, void* d_ws, size_t ws_size,
                              hipStream_t stream) {
    const float* x     = (const float*)d_in[0];
    const float* tree  = (const float*)d_in[1];
    const float* W1    = (const float*)d_in[2];
    const float* b1    = (const float*)d_in[3];
    const float* W2    = (const float*)d_in[4];
    const float* b2    = (const float*)d_in[5];
    const float* W3    = (const float*)d_in[6];
    const float* b3    = (const float*)d_in[7];
    const float* W4    = (const float*)d_in[8];
    const float* b4    = (const float*)d_in[9];
    const float* gamma = (const float*)d_in[10];
    const float* beta  = (const float*)d_in[11];
    const float* W5    = (const float*)d_in[12];
    const float* b5    = (const float*)d_in[13];
    float* out = (float*)d_out;

    float* h = (float*)d_ws;              // 16384*64 f32 = 4 MB
    float* m = h + 16384 * 64;            // 32*2048  f32 = 256 KB
    float* y = m + 32 * 2048;             // 32*64    f32 = 8 KB

    k_micro   <<<4096,          256, 0, stream>>>(x, W1, b1, W2, b2, h);
    k_agg_macro<<<dim3(16, 32), 256, 0, stream>>>(h, tree, W3, b3, m);
    k_fout1   <<<32,            256, 0, stream>>>(m, W4, b4, y);
    k_bn_out  <<<1,             320, 0, stream>>>(y, gamma, beta, W5, b5, out);
}

// Round 2
// 41.107 us; speedup vs baseline: 1.7279x; 1.7279x over previous
//
#include <hip/hip_runtime.h>

// Problem constants (reference): B=32, L=512, N=128, IN=16, OUT=10
// Pipeline:
//   kA: h = relu(relu(x@W1+b1)@W2+b2)                  (B*L, 64)
//   kB: h_agg = max_l h*tree ; m = relu(h_agg@W3+b3)   (B, N*16)
//   kC: part[b][s][o] = partial dot of m@W4 (split-K)  (B, 8, 64)
//   kD: y=relu(sum part+b4); BN(batch stats); @W5+b5   (B, 10)

__global__ __launch_bounds__(256) void k_micro(
    const float* __restrict__ x, const float* __restrict__ W1,
    const float* __restrict__ b1, const float* __restrict__ W2,
    const float* __restrict__ b2, float* __restrict__ h)
{
    const int tid = threadIdx.x;
    const int r = tid >> 6;                 // row within block (0..3)
    const int c = tid & 63;                 // channel lane
    const int row = blockIdx.x * 4 + r;     // 0..16383 (= b*512 + l)

    __shared__ float sx[4][16];
    __shared__ float sh1[4][32];

    if (c < 16) sx[r][c] = x[row * 16 + c];
    __syncthreads();

    if (c < 32) {
        float a = b1[c];
        #pragma unroll
        for (int i = 0; i < 16; ++i) a += sx[r][i] * W1[i * 32 + c];
        sh1[r][c] = fmaxf(a, 0.f);
    }
    __syncthreads();

    float a = b2[c];
    #pragma unroll
    for (int j = 0; j < 32; ++j) a += sh1[r][j] * W2[j * 64 + c];
    h[(size_t)row * 64 + c] = fmaxf(a, 0.f);
}

// One block per (node-group of 8, batch b). 256 threads = 4 leaf-phases x 64 ch.
__global__ __launch_bounds__(256) void k_agg_macro(
    const float* __restrict__ h,     // [B][512][64]
    const float* __restrict__ tree,  // [128][512]
    const float* __restrict__ W3, const float* __restrict__ b3,
    float* __restrict__ m)           // [B][2048]
{
    const int ng  = blockIdx.x;      // 0..15 (8 nodes each)
    const int b   = blockIdx.y;      // 0..31
    const int tid = threadIdx.x;
    const int g   = tid >> 6;        // leaf phase 0..3
    const int c   = tid & 63;        // channel

    __shared__ __align__(16) float tl[512][8];   // transposed tree tile
    __shared__ float sred[4][8][64];
    __shared__ float sagg[8][64];

    // stage tree tile transposed: tl[l][n] = tree[ng*8+n][l]
    for (int idx = tid; idx < 8 * 512; idx += 256) {
        int n = idx >> 9, l = idx & 511;
        tl[l][n] = tree[(ng * 8 + n) * 512 + l];
    }
    __syncthreads();

    float acc[8];
    #pragma unroll
    for (int j = 0; j < 8; ++j) acc[j] = 0.f;   // products are >=0, 0-init exact

    const float* hb = h + (size_t)b * 512 * 64 + c;
    #pragma unroll 4
    for (int l = g; l < 512; l += 4) {
        float hv = hb[(size_t)l * 64];
        const float4* tp = (const float4*)&tl[l][0];
        float4 t0 = tp[0], t1 = tp[1];          // 8 node masks, broadcast
        acc[0] = fmaxf(acc[0], hv * t0.x);
        acc[1] = fmaxf(acc[1], hv * t0.y);
        acc[2] = fmaxf(acc[2], hv * t0.z);
        acc[3] = fmaxf(acc[3], hv * t0.w);
        acc[4] = fmaxf(acc[4], hv * t1.x);
        acc[5] = fmaxf(acc[5], hv * t1.y);
        acc[6] = fmaxf(acc[6], hv * t1.z);
        acc[7] = fmaxf(acc[7], hv * t1.w);
    }

    #pragma unroll
    for (int j = 0; j < 8; ++j) sred[g][j][c] = acc[j];
    __syncthreads();

    // combine 4 leaf-phases
    for (int idx = tid; idx < 8 * 64; idx += 256) {
        int n = idx >> 6, cc = idx & 63;
        sagg[n][cc] = fmaxf(fmaxf(sred[0][n][cc], sred[1][n][cc]),
                            fmaxf(sred[2][n][cc], sred[3][n][cc]));
    }
    __syncthreads();

    // fused f_macro: m[n][j] = relu(b3[j] + sum_c h_agg[n][c]*W3[c][j])
    if (tid < 128) {
        int n = tid >> 4, j = tid & 15;
        float a = b3[j];
        #pragma unroll
        for (int cc = 0; cc < 64; ++cc) a += sagg[n][cc] * W3[cc * 16 + j];
        int node = ng * 8 + n;
        m[(size_t)b * 2048 + node * 16 + j] = fmaxf(a, 0.f);
    }
}

// Split-K phase A of y = m@W4: part[b][s][o] = sum_{k in slice s} m[b][k]*W4[k][o]
// grid (32, 8), 256 threads = 4 k-phases x 64 outputs. 1024 waves total.
__global__ __launch_bounds__(256) void k_fout1_partial(
    const float* __restrict__ m, const float* __restrict__ W4,
    float* __restrict__ part)
{
    const int b   = blockIdx.x;      // 0..31
    const int s   = blockIdx.y;      // 0..7 (k-slice of 256)
    const int tid = threadIdx.x;
    const int g = tid >> 6, o = tid & 63;

    __shared__ float sm[256];
    __shared__ float sred[4][64];

    sm[tid] = m[(size_t)b * 2048 + s * 256 + tid];
    __syncthreads();

    float acc = 0.f;
    const float* w = W4 + (size_t)(s * 256) * 64 + o;
    #pragma unroll 8
    for (int k = g; k < 256; k += 4)
        acc += sm[k] * w[(size_t)k * 64];
    sred[g][o] = acc;
    __syncthreads();

    if (tid < 64)
        part[((size_t)b * 8 + s) * 64 + o] =
            sred[0][o] + sred[1][o] + sred[2][o] + sred[3][o];
}

// Combine partials + bias + ReLU -> y; BatchNorm (batch stats over B=32);
// final linear (64->10). One block, 1024 threads.
__global__ __launch_bounds__(1024) void k_bn_out(
    const float* __restrict__ part, const float* __restrict__ b4,
    const float* __restrict__ gamma, const float* __restrict__ beta,
    const float* __restrict__ W5, const float* __restrict__ b5,
    float* __restrict__ out)
{
    const int tid = threadIdx.x;
    __shared__ float sy[32 * 64];
    __shared__ float smean[64], sscale[64], sbeta[64];

    // y[b][o] = relu(b4[o] + sum_s part[b][s][o])
    #pragma unroll
    for (int idx = tid; idx < 2048; idx += 1024) {
        int b = idx >> 6, o = idx & 63;
        float v = b4[o];
        #pragma unroll
        for (int s = 0; s < 8; ++s) v += part[((size_t)b * 8 + s) * 64 + o];
        sy[idx] = fmaxf(v, 0.f);
    }
    __syncthreads();

    if (tid < 64) {
        float s1 = 0.f, s2 = 0.f;
        #pragma unroll
        for (int b = 0; b < 32; ++b) {
            float v = sy[b * 64 + tid];
            s1 += v; s2 += v * v;
        }
        float mean = s1 * (1.f / 32.f);
        float var  = s2 * (1.f / 32.f) - mean * mean;  // biased, as torch BN
        smean[tid]  = mean;
        sscale[tid] = gamma[tid] * rsqrtf(var + 1e-5f);
        sbeta[tid]  = beta[tid];
    }
    __syncthreads();

    if (tid < 320) {
        int b = tid / 10, q = tid % 10;
        float acc = b5[q];
        #pragma unroll
        for (int o = 0; o < 64; ++o)
            acc += ((sy[b * 64 + o] - smean[o]) * sscale[o] + sbeta[o])
                   * W5[o * 10 + q];
        out[b * 10 + q] = acc;
    }
}

extern "C" void kernel_launch(void* const* d_in, const int* in_sizes, int n_in,
                              void* d_out, int out_size, void* d_ws, size_t ws_size,
                              hipStream_t stream) {
    const float* x     = (const float*)d_in[0];
    const float* tree  = (const float*)d_in[1];
    const float* W1    = (const float*)d_in[2];
    const float* b1    = (const float*)d_in[3];
    const float* W2    = (const float*)d_in[4];
    const float* b2    = (const float*)d_in[5];
    const float* W3    = (const float*)d_in[6];
    const float* b3    = (const float*)d_in[7];
    const float* W4    = (const float*)d_in[8];
    const float* b4    = (const float*)d_in[9];
    const float* gamma = (const float*)d_in[10];
    const float* beta  = (const float*)d_in[11];
    const float* W5    = (const float*)d_in[12];
    const float* b5    = (const float*)d_in[13];
    float* out = (float*)d_out;

    float* h    = (float*)d_ws;           // 16384*64 f32 = 4 MB
    float* m    = h + 16384 * 64;         // 32*2048  f32 = 256 KB
    float* part = m + 32 * 2048;          // 32*8*64  f32 = 64 KB

    k_micro         <<<4096,         256, 0, stream>>>(x, W1, b1, W2, b2, h);
    k_agg_macro     <<<dim3(16, 32), 256, 0, stream>>>(h, tree, W3, b3, m);
    k_fout1_partial <<<dim3(32, 8),  256, 0, stream>>>(m, W4, part);
    k_bn_out        <<<1,           1024, 0, stream>>>(part, b4, gamma, beta, W5, b5, out);
}